// Round 8
// baseline (332.286 us; speedup 1.0000x reference)
//
#include <hip/hip_runtime.h>
#include <math.h>

#define B_ 2
#define C_ 36
#define H_ 512
#define W_ 512
#define K_ 9
#define HW_ (H_ * W_)
#define ROWF4 (W_ * C_ / 4)  // float4 pitch of one image row in featT = 4608

// ---------------------------------------------------------------------------
// Transpose features [B,C,H,W] -> [B,H,W,C].
// ---------------------------------------------------------------------------
__global__ __launch_bounds__(256) void transpose_kernel(const float* __restrict__ in,
                                                        float* __restrict__ out) {
  __shared__ float tile[64][37];
  int blk = blockIdx.x;  // ((b*H + h)*8 + wt)
  int wt = blk & 7;
  int h = (blk >> 3) & (H_ - 1);
  int b = blk >> 12;
  int w0 = wt << 6;
  int tid = threadIdx.x;
  const float* src = in + ((size_t)b * C_) * HW_ + (size_t)h * W_ + w0;
#pragma unroll
  for (int it = 0; it < 9; ++it) {
    int idx = it * 256 + tid;
    int c = idx >> 6;
    int wl = idx & 63;
    tile[wl][c] = src[(size_t)c * HW_ + wl];
  }
  __syncthreads();
  float* dst = out + (((size_t)b * H_ + h) * W_ + w0) * C_;
#pragma unroll
  for (int it = 0; it < 9; ++it) {
    int idx = it * 256 + tid;
    int wl = idx / 36;
    int c = idx - wl * 36;
    dst[idx] = tile[wl][c];
  }
}

// ---------------------------------------------------------------------------
// Wave-cooperative eval v6: 256-thread WG = 4 waves, each owning an 8x8 pixel
// tile (2x2 sub-tiles of a 16x16 super-tile) and a PRIVATE LDS slice.
// v5 lesson: the per-k __syncthreads() is load-bearing — its waitcnt drain
// orders the meta ds_write before the gather ds_reads (removing it raced).
// It stays, now as a true 4-wave barrier (uniform k-loop, no divergence).
// Within a k, the scr RAW/WAR hazards are barrier-free (validated in v6/r6).
// launch_bounds(256,3): VGPR cap 170 >= est ~140, no spills (v5's 128-cap
// spilled and blew replay time to 578us).
// ---------------------------------------------------------------------------
__global__ __launch_bounds__(256, 3) void eval_kernel_cw(const float* __restrict__ feat,
                                                         const float* __restrict__ offx,
                                                         const float* __restrict__ offy,
                                                         float* __restrict__ out) {
  __shared__ __align__(16) float scratch[4][32 * 36];  // per-wave [task&31][36ch]
  __shared__ __align__(16) float4 w_lds[4][64];        // per-wave bilinear weights
  __shared__ int a_lds[4][64];                         // per-wave row0-run base idx

  int tid = threadIdx.x;
  int wv = tid >> 6;  // wave 0..3
  int lane = tid & 63;
  int blk = blockIdx.x;
  int region = blk & 7;  // XCD round-robin residue -> fixed 256x256 region
  int slot = blk >> 3;   // 0..255 within region: 16x16 super-tiles
  int b = region >> 2;
  int qd = region & 3;
  int qy = (qd >> 1) << 8;
  int qx = (qd & 1) << 8;
  int tr = slot >> 4;  // super-tile row 0..15
  int tc = slot & 15;
  if (tr & 1) tc = 15 - tc;  // serpentine for window overlap on same XCD
  int sy = (wv >> 1) << 3;   // sub-tile offset within 16x16
  int sx = (wv & 1) << 3;
  int h = qy + tr * 16 + sy + (lane >> 3);
  int w = qx + tc * 16 + sx + (lane & 7);
  int ph = h * W_ + w;
  int p = b * HW_ + ph;

  const float4* feat4 = reinterpret_cast<const float4*>(feat);
  float* scr = scratch[wv];
  float4* wl_ = w_lds[wv];
  int* al_ = a_lds[wv];

  const float* oxb = offx + (size_t)b * K_ * HW_ + ph;
  const float* oyb = offy + (size_t)b * K_ * HW_ + ph;

  // own pixel's 36 center features -> registers
  float F[C_];
  {
    const float4* myF = feat4 + (size_t)p * 9;
#pragma unroll
    for (int i = 0; i < 9; ++i) {
      float4 v = myF[i];
      F[4 * i + 0] = v.x; F[4 * i + 1] = v.y; F[4 * i + 2] = v.z; F[4 * i + 3] = v.w;
    }
  }

  int g = lane / 9;      // gather group 0..7 (g==7 -> lane 63, stores suppressed)
  int q = lane - 9 * g;  // channel-quad within task

  float lx = (float)w;
  float ly = (float)h;

  float M = -INFINITY, den = 0.f, axs = 0.f, ays = 0.f;

#pragma unroll 1
  for (int k = 0; k < K_; ++k) {
    // --- meta for my task ---
    float ox = oxb[k * HW_];
    float oy = oyb[k * HW_];
    float rx = fminf(fmaxf(lx + ox, 0.0f), 511.0f);
    float ry = fminf(fmaxf(ly + oy, 0.0f), 511.0f);
    float gx = (rx - 255.5f) / 255.5f;
    float gy = (ry - 255.5f) / 255.5f;
    float px = (gx + 1.0f) * 0.5f * 511.0f;
    float py = (gy + 1.0f) * 0.5f * 511.0f;
    int x0 = (int)floorf(px); x0 = (x0 > 510) ? 510 : x0;
    int y0 = (int)floorf(py); y0 = (y0 > 510) ? 510 : y0;
    float wx = px - (float)x0;
    float wy = py - (float)y0;
    wl_[lane] = make_float4((1.0f - wx) * (1.0f - wy), wx * (1.0f - wy),
                            (1.0f - wx) * wy, wx * wy);
    al_[lane] = ((b * H_ + y0) * W_ + x0) * 9;  // float4 index of row0 run
    __syncthreads();  // load-bearing: drains meta ds_writes before gather reads

    float4 L[5][4];
    // --- issue phase A (tasks 0..31): ~20 loads in flight ---
#pragma unroll
    for (int r = 0; r < 5; ++r) {
      int tt = 7 * r + g;
      int t = (tt > 31) ? 31 : tt;
      const float4* r0 = feat4 + al_[t];
      L[r][0] = r0[q];
      L[r][1] = r0[9 + q];
      L[r][2] = r0[ROWF4 + q];
      L[r][3] = r0[ROWF4 + 9 + q];
    }
    // --- consume phase A ---
#pragma unroll
    for (int r = 0; r < 5; ++r) {
      int tt = 7 * r + g;
      int t = (tt > 31) ? 31 : tt;
      float4 W4 = wl_[t];
      float4 v00 = L[r][0], v01 = L[r][1], v10 = L[r][2], v11 = L[r][3];
      float4 a4;
      a4.x = W4.x * v00.x + W4.y * v01.x + W4.z * v10.x + W4.w * v11.x;
      a4.y = W4.x * v00.y + W4.y * v01.y + W4.z * v10.y + W4.w * v11.y;
      a4.z = W4.x * v00.z + W4.y * v01.z + W4.z * v10.z + W4.w * v11.z;
      a4.w = W4.x * v00.w + W4.y * v01.w + W4.z * v10.w + W4.w * v11.w;
      if (tt < 32 && lane < 63) {
        *reinterpret_cast<float4*>(&scr[t * 36 + 4 * q]) = a4;
      }
    }
    // --- issue phase B (tasks 32..63) BEFORE the phase-A reduce ---
#pragma unroll
    for (int r = 0; r < 5; ++r) {
      int tt = 32 + 7 * r + g;
      int t = (tt > 63) ? 63 : tt;
      const float4* r0 = feat4 + al_[t];
      L[r][0] = r0[q];
      L[r][1] = r0[9 + q];
      L[r][2] = r0[ROWF4 + q];
      L[r][3] = r0[ROWF4 + 9 + q];
    }
    // --- phase-A owner reduce + softmax (lanes 0..31); in-order DS makes the
    //     scr write->read safe barrier-free (validated round 6) ---
    if (lane < 32) {
      float D[9] = {0.f, 0.f, 0.f, 0.f, 0.f, 0.f, 0.f, 0.f, 0.f};
      const float4* sc = reinterpret_cast<const float4*>(&scr[lane * 36]);
#pragma unroll
      for (int q2 = 0; q2 < 9; ++q2) {
        float4 a4 = sc[q2];
        float av[4] = {a4.x, a4.y, a4.z, a4.w};
        int ga = q2 / 3;
        int f0 = 4 * (q2 % 3);
#pragma unroll
        for (int j = 0; j < 4; ++j) {
          D[ga]     += fabsf(F[f0 + j]      - av[j]);
          D[3 + ga] += fabsf(F[12 + f0 + j] - av[j]);
          D[6 + ga] += fabsf(F[24 + f0 + j] - av[j]);
        }
      }
      float mn = D[0];
#pragma unroll
      for (int j = 1; j < 9; ++j) mn = fminf(mn, D[j]);
      float xk = -(mn / 12.0f) * 1000.0f;
      float nm = fmaxf(M, xk);
      float scl = expf(M - nm);
      float ek = expf(xk - nm);
      den = den * scl + ek;
      axs = axs * scl + ox * ek;
      ays = ays * scl + oy * ek;
      M = nm;
    }
    // --- consume phase B (in-order DS: these writes follow the reads above) ---
#pragma unroll
    for (int r = 0; r < 5; ++r) {
      int tt = 32 + 7 * r + g;
      int t = (tt > 63) ? 63 : tt;
      float4 W4 = wl_[t];
      float4 v00 = L[r][0], v01 = L[r][1], v10 = L[r][2], v11 = L[r][3];
      float4 a4;
      a4.x = W4.x * v00.x + W4.y * v01.x + W4.z * v10.x + W4.w * v11.x;
      a4.y = W4.x * v00.y + W4.y * v01.y + W4.z * v10.y + W4.w * v11.y;
      a4.z = W4.x * v00.z + W4.y * v01.z + W4.z * v10.z + W4.w * v11.z;
      a4.w = W4.x * v00.w + W4.y * v01.w + W4.z * v10.w + W4.w * v11.w;
      if (tt < 64 && lane < 63) {
        *reinterpret_cast<float4*>(&scr[(t - 32) * 36 + 4 * q]) = a4;
      }
    }
    // --- phase-B owner reduce + softmax (lanes 32..63) ---
    if (lane >= 32) {
      float D[9] = {0.f, 0.f, 0.f, 0.f, 0.f, 0.f, 0.f, 0.f, 0.f};
      const float4* sc = reinterpret_cast<const float4*>(&scr[(lane - 32) * 36]);
#pragma unroll
      for (int q2 = 0; q2 < 9; ++q2) {
        float4 a4 = sc[q2];
        float av[4] = {a4.x, a4.y, a4.z, a4.w};
        int ga = q2 / 3;
        int f0 = 4 * (q2 % 3);
#pragma unroll
        for (int j = 0; j < 4; ++j) {
          D[ga]     += fabsf(F[f0 + j]      - av[j]);
          D[3 + ga] += fabsf(F[12 + f0 + j] - av[j]);
          D[6 + ga] += fabsf(F[24 + f0 + j] - av[j]);
        }
      }
      float mn = D[0];
#pragma unroll
      for (int j = 1; j < 9; ++j) mn = fminf(mn, D[j]);
      float xk = -(mn / 12.0f) * 1000.0f;
      float nm = fmaxf(M, xk);
      float scl = expf(M - nm);
      float ek = expf(xk - nm);
      den = den * scl + ek;
      axs = axs * scl + ox * ek;
      ays = ays * scl + oy * ek;
      M = nm;
    }
  }

  float resx = axs / den;
  float resy = ays / den;
  out[p] = fminf(fmaxf(resx + lx, 0.0f), 511.0f) - lx;
  out[B_ * HW_ + p] = fminf(fmaxf(resy + ly, 0.0f), 511.0f) - ly;
}

// Fallback (no scratch): original channel-major layout, thread-per-pixel.
__global__ __launch_bounds__(256) void eval_kernel_n(const float* __restrict__ feat,
                                                     const float* __restrict__ offx,
                                                     const float* __restrict__ offy,
                                                     float* __restrict__ out) {
  int p = blockIdx.x * 256 + threadIdx.x;
  int ph = p & (HW_ - 1);
  int b = p >> 18;
  float F[C_];
  const float* fb = feat + (size_t)b * C_ * HW_ + ph;
#pragma unroll
  for (int c = 0; c < C_; ++c) F[c] = fb[(size_t)c * HW_];
  float lx = (float)(ph & (W_ - 1));
  float ly = (float)((ph >> 9) & (H_ - 1));
  const float* oxb = offx + (size_t)b * K_ * HW_ + ph;
  const float* oyb = offy + (size_t)b * K_ * HW_ + ph;
  float M = -INFINITY, den = 0.f, ax = 0.f, ay = 0.f;
#pragma unroll 1
  for (int k = 0; k < K_; ++k) {
    float ox = oxb[k * HW_];
    float oy = oyb[k * HW_];
    float rx = fminf(fmaxf(lx + ox, 0.0f), 511.0f);
    float ry = fminf(fmaxf(ly + oy, 0.0f), 511.0f);
    float gx = (rx - 255.5f) / 255.5f;
    float gy = (ry - 255.5f) / 255.5f;
    float px = (gx + 1.0f) * 0.5f * 511.0f;
    float py = (gy + 1.0f) * 0.5f * 511.0f;
    int x0 = (int)floorf(px); x0 = (x0 > 510) ? 510 : x0;
    int y0 = (int)floorf(py); y0 = (y0 > 510) ? 510 : y0;
    float wx = px - (float)x0;
    float wy = py - (float)y0;
    float w00 = (1.0f - wx) * (1.0f - wy);
    float w01 = wx * (1.0f - wy);
    float w10 = (1.0f - wx) * wy;
    float w11 = wx * wy;
    float D[9] = {0.f, 0.f, 0.f, 0.f, 0.f, 0.f, 0.f, 0.f, 0.f};
    const float* pl = feat + (size_t)b * C_ * HW_ + (size_t)y0 * W_ + x0;
#pragma unroll
    for (int c = 0; c < C_; ++c) {
      const float* q0 = pl + (size_t)c * HW_;
      float v00 = q0[0], v01 = q0[1];
      float v10 = q0[W_], v11 = q0[W_ + 1];
      float a = v00 * w00 + v01 * w01 + v10 * w10 + v11 * w11;
      int i = c % 12;
      int ga = c / 12;
      D[ga]     += fabsf(F[i]      - a);
      D[3 + ga] += fabsf(F[12 + i] - a);
      D[6 + ga] += fabsf(F[24 + i] - a);
    }
    float mn = D[0];
#pragma unroll
    for (int j = 1; j < 9; ++j) mn = fminf(mn, D[j]);
    float xk = -(mn / 12.0f) * 1000.0f;
    float nm = fmaxf(M, xk);
    float sc = expf(M - nm);
    float ek = expf(xk - nm);
    den = den * sc + ek;
    ax = ax * sc + ox * ek;
    ay = ay * sc + oy * ek;
    M = nm;
  }
  float resx = ax / den;
  float resy = ay / den;
  out[p] = fminf(fmaxf(resx + lx, 0.0f), 511.0f) - lx;
  out[B_ * HW_ + p] = fminf(fmaxf(resy + ly, 0.0f), 511.0f) - ly;
}

extern "C" void kernel_launch(void* const* d_in, const int* in_sizes, int n_in,
                              void* d_out, int out_size, void* d_ws, size_t ws_size,
                              hipStream_t stream) {
  const float* features = (const float*)d_in[0];
  const float* offset_x = (const float*)d_in[1];
  const float* offset_y = (const float*)d_in[2];
  float* out = (float*)d_out;

  const int npix = B_ * HW_;  // 524288
  const size_t need = (size_t)npix * C_ * sizeof(float);  // 75.5 MB

  if (ws_size >= need) {
    float* featT = (float*)d_ws;
    transpose_kernel<<<B_ * H_ * (W_ / 64), 256, 0, stream>>>(features, featT);
    eval_kernel_cw<<<npix / 256, 256, 0, stream>>>(featT, offset_x, offset_y, out);
  } else {
    eval_kernel_n<<<npix / 256, 256, 0, stream>>>(features, offset_x, offset_y, out);
  }
}

// Round 9
// 324.958 us; speedup vs baseline: 1.0226x; 1.0226x over previous
//
#include <hip/hip_runtime.h>
#include <math.h>

#define B_ 2
#define C_ 36
#define H_ 512
#define W_ 512
#define K_ 9
#define HW_ (H_ * W_)
#define ROWF4 (W_ * C_ / 4)  // float4 pitch of one image row in featT = 4608

// ---------------------------------------------------------------------------
// Transpose features [B,C,H,W] -> [B,H,W,C].
// ---------------------------------------------------------------------------
__global__ __launch_bounds__(256) void transpose_kernel(const float* __restrict__ in,
                                                        float* __restrict__ out) {
  __shared__ float tile[64][37];
  int blk = blockIdx.x;  // ((b*H + h)*8 + wt)
  int wt = blk & 7;
  int h = (blk >> 3) & (H_ - 1);
  int b = blk >> 12;
  int w0 = wt << 6;
  int tid = threadIdx.x;
  const float* src = in + ((size_t)b * C_) * HW_ + (size_t)h * W_ + w0;
#pragma unroll
  for (int it = 0; it < 9; ++it) {
    int idx = it * 256 + tid;
    int c = idx >> 6;
    int wl = idx & 63;
    tile[wl][c] = src[(size_t)c * HW_ + wl];
  }
  __syncthreads();
  float* dst = out + (((size_t)b * H_ + h) * W_ + w0) * C_;
#pragma unroll
  for (int it = 0; it < 9; ++it) {
    int idx = it * 256 + tid;
    int wl = idx / 36;
    int c = idx - wl * 36;
    dst[idx] = tile[wl][c];
  }
}

// ---------------------------------------------------------------------------
// Wave-cooperative eval v8: 256-thread WG = 4 fully independent waves, each
// owning an 8x8 tile + a private LDS scr slice. META VIA SHUFFLES: each lane
// keeps its own pixel's (w00,w01,w10,w11,base) in registers; gather lanes get
// task t's meta with __shfl (ds_bpermute — register-based, no LDS hazard).
// ZERO __syncthreads: r8 showed the 4-wave barrier's vmcnt(0) drain cost
// ~17us and doubled FETCH by killing cross-k load overlap. The only LDS use
// left is scr (interp results): same-array ds_write->ds_read, in-order DS
// pipe per wave — validated barrier-free across r5/r6/r8.
// Depth-5 flat load window (~20 loads in flight) + next-k offset prefetch.
// launch_bounds(256,3): VGPR cap 170 >= est ~145 (v5 lesson: cap 128 spilled).
// ---------------------------------------------------------------------------
__global__ __launch_bounds__(256, 3) void eval_kernel_cw(const float* __restrict__ feat,
                                                         const float* __restrict__ offx,
                                                         const float* __restrict__ offy,
                                                         float* __restrict__ out) {
  __shared__ __align__(16) float scratch[4][64 * 36];  // per-wave [task][36ch]

  int tid = threadIdx.x;
  int wv = tid >> 6;  // wave 0..3
  int lane = tid & 63;
  int blk = blockIdx.x;
  int region = blk & 7;  // XCD round-robin residue -> fixed 256x256 region
  int slot = blk >> 3;   // 0..255 within region: 16x16 super-tiles
  int b = region >> 2;
  int qd = region & 3;
  int qy = (qd >> 1) << 8;
  int qx = (qd & 1) << 8;
  int tr = slot >> 4;  // super-tile row 0..15
  int tc = slot & 15;
  if (tr & 1) tc = 15 - tc;  // serpentine for window overlap on same XCD
  int sy = (wv >> 1) << 3;   // sub-tile offset within 16x16
  int sx = (wv & 1) << 3;
  int h = qy + tr * 16 + sy + (lane >> 3);
  int w = qx + tc * 16 + sx + (lane & 7);
  int ph = h * W_ + w;
  int p = b * HW_ + ph;

  const float4* feat4 = reinterpret_cast<const float4*>(feat);
  float* scr = scratch[wv];

  const float* oxb = offx + (size_t)b * K_ * HW_ + ph;
  const float* oyb = offy + (size_t)b * K_ * HW_ + ph;

  // own pixel's 36 center features -> registers
  float F[C_];
  {
    const float4* myF = feat4 + (size_t)p * 9;
#pragma unroll
    for (int i = 0; i < 9; ++i) {
      float4 v = myF[i];
      F[4 * i + 0] = v.x; F[4 * i + 1] = v.y; F[4 * i + 2] = v.z; F[4 * i + 3] = v.w;
    }
  }

  int g = lane / 9;      // gather group 0..6 (lane 63: g=7, stores suppressed)
  int q = lane - 9 * g;  // channel-quad within task

  float lx = (float)w;
  float ly = (float)h;

  float M = -INFINITY, den = 0.f, axs = 0.f, ays = 0.f;

  // software-pipelined offset loads (k+1 prefetched during k)
  float oxc = oxb[0];
  float oyc = oyb[0];

#pragma unroll 1
  for (int k = 0; k < K_; ++k) {
    float ox = oxc;
    float oy = oyc;
    if (k + 1 < K_) {
      oxc = oxb[(k + 1) * HW_];
      oyc = oyb[(k + 1) * HW_];
    }
    // --- meta for MY pixel, candidate k (registers only) ---
    float rx = fminf(fmaxf(lx + ox, 0.0f), 511.0f);
    float ry = fminf(fmaxf(ly + oy, 0.0f), 511.0f);
    float gx = (rx - 255.5f) / 255.5f;
    float gy = (ry - 255.5f) / 255.5f;
    float px = (gx + 1.0f) * 0.5f * 511.0f;
    float py = (gy + 1.0f) * 0.5f * 511.0f;
    int x0 = (int)floorf(px); x0 = (x0 > 510) ? 510 : x0;
    int y0 = (int)floorf(py); y0 = (y0 > 510) ? 510 : y0;
    float wx = px - (float)x0;
    float wy = py - (float)y0;
    float w00 = (1.0f - wx) * (1.0f - wy);
    float w01 = wx * (1.0f - wy);
    float w10 = (1.0f - wx) * wy;
    float w11 = wx * wy;
    int base = ((b * H_ + y0) * W_ + x0) * 9;  // float4 index of row0 run

    float4 L[5][4];
    // --- issue rounds 0..4: ~20 loads in flight; base via shuffle ---
#pragma unroll
    for (int r = 0; r < 5; ++r) {
      int tt = 7 * r + g;
      int t = (tt > 63) ? 63 : tt;
      int bt = __shfl(base, t);
      const float4* r0 = feat4 + bt;
      L[r][0] = r0[q];
      L[r][1] = r0[9 + q];
      L[r][2] = r0[ROWF4 + q];
      L[r][3] = r0[ROWF4 + 9 + q];
    }
    // --- steady state: consume round r, issue round r+5 ---
#pragma unroll
    for (int r = 0; r < 10; ++r) {
      int s = r % 5;
      int tt = 7 * r + g;
      int t = (tt > 63) ? 63 : tt;
      float W00 = __shfl(w00, t);
      float W01 = __shfl(w01, t);
      float W10 = __shfl(w10, t);
      float W11 = __shfl(w11, t);
      float4 v00 = L[s][0], v01 = L[s][1], v10 = L[s][2], v11 = L[s][3];
      float4 a4;
      a4.x = W00 * v00.x + W01 * v01.x + W10 * v10.x + W11 * v11.x;
      a4.y = W00 * v00.y + W01 * v01.y + W10 * v10.y + W11 * v11.y;
      a4.z = W00 * v00.z + W01 * v01.z + W10 * v10.z + W11 * v11.z;
      a4.w = W00 * v00.w + W01 * v01.w + W10 * v10.w + W11 * v11.w;
      if (tt < 64 && lane < 63) {
        *reinterpret_cast<float4*>(&scr[t * 36 + 4 * q]) = a4;
      }
      if (r + 5 < 10) {
        int tt2 = 7 * (r + 5) + g;
        int t2 = (tt2 > 63) ? 63 : tt2;
        int bt2 = __shfl(base, t2);
        const float4* r0 = feat4 + bt2;
        L[s][0] = r0[q];
        L[s][1] = r0[9 + q];
        L[s][2] = r0[ROWF4 + q];
        L[s][3] = r0[ROWF4 + 9 + q];
      }
    }

    // --- owner reduce (in-order DS: all scr writes above precede these reads) ---
    float D[9] = {0.f, 0.f, 0.f, 0.f, 0.f, 0.f, 0.f, 0.f, 0.f};
    const float4* sc = reinterpret_cast<const float4*>(&scr[lane * 36]);
#pragma unroll
    for (int q2 = 0; q2 < 9; ++q2) {
      float4 a4 = sc[q2];
      float av[4] = {a4.x, a4.y, a4.z, a4.w};
      int ga = q2 / 3;
      int f0 = 4 * (q2 % 3);
#pragma unroll
      for (int j = 0; j < 4; ++j) {
        D[ga]     += fabsf(F[f0 + j]      - av[j]);
        D[3 + ga] += fabsf(F[12 + f0 + j] - av[j]);
        D[6 + ga] += fabsf(F[24 + f0 + j] - av[j]);
      }
    }
    float mn = D[0];
#pragma unroll
    for (int j = 1; j < 9; ++j) mn = fminf(mn, D[j]);
    float xk = -(mn / 12.0f) * 1000.0f;

    float nm = fmaxf(M, xk);
    float scl = expf(M - nm);
    float ek = expf(xk - nm);
    den = den * scl + ek;
    axs = axs * scl + ox * ek;
    ays = ays * scl + oy * ek;
    M = nm;
  }

  float resx = axs / den;
  float resy = ays / den;
  out[p] = fminf(fmaxf(resx + lx, 0.0f), 511.0f) - lx;
  out[B_ * HW_ + p] = fminf(fmaxf(resy + ly, 0.0f), 511.0f) - ly;
}

// Fallback (no scratch): original channel-major layout, thread-per-pixel.
__global__ __launch_bounds__(256) void eval_kernel_n(const float* __restrict__ feat,
                                                     const float* __restrict__ offx,
                                                     const float* __restrict__ offy,
                                                     float* __restrict__ out) {
  int p = blockIdx.x * 256 + threadIdx.x;
  int ph = p & (HW_ - 1);
  int b = p >> 18;
  float F[C_];
  const float* fb = feat + (size_t)b * C_ * HW_ + ph;
#pragma unroll
  for (int c = 0; c < C_; ++c) F[c] = fb[(size_t)c * HW_];
  float lx = (float)(ph & (W_ - 1));
  float ly = (float)((ph >> 9) & (H_ - 1));
  const float* oxb = offx + (size_t)b * K_ * HW_ + ph;
  const float* oyb = offy + (size_t)b * K_ * HW_ + ph;
  float M = -INFINITY, den = 0.f, ax = 0.f, ay = 0.f;
#pragma unroll 1
  for (int k = 0; k < K_; ++k) {
    float ox = oxb[k * HW_];
    float oy = oyb[k * HW_];
    float rx = fminf(fmaxf(lx + ox, 0.0f), 511.0f);
    float ry = fminf(fmaxf(ly + oy, 0.0f), 511.0f);
    float gx = (rx - 255.5f) / 255.5f;
    float gy = (ry - 255.5f) / 255.5f;
    float px = (gx + 1.0f) * 0.5f * 511.0f;
    float py = (gy + 1.0f) * 0.5f * 511.0f;
    int x0 = (int)floorf(px); x0 = (x0 > 510) ? 510 : x0;
    int y0 = (int)floorf(py); y0 = (y0 > 510) ? 510 : y0;
    float wx = px - (float)x0;
    float wy = py - (float)y0;
    float w00 = (1.0f - wx) * (1.0f - wy);
    float w01 = wx * (1.0f - wy);
    float w10 = (1.0f - wx) * wy;
    float w11 = wx * wy;
    float D[9] = {0.f, 0.f, 0.f, 0.f, 0.f, 0.f, 0.f, 0.f, 0.f};
    const float* pl = feat + (size_t)b * C_ * HW_ + (size_t)y0 * W_ + x0;
#pragma unroll
    for (int c = 0; c < C_; ++c) {
      const float* q0 = pl + (size_t)c * HW_;
      float v00 = q0[0], v01 = q0[1];
      float v10 = q0[W_], v11 = q0[W_ + 1];
      float a = v00 * w00 + v01 * w01 + v10 * w10 + v11 * w11;
      int i = c % 12;
      int ga = c / 12;
      D[ga]     += fabsf(F[i]      - a);
      D[3 + ga] += fabsf(F[12 + i] - a);
      D[6 + ga] += fabsf(F[24 + i] - a);
    }
    float mn = D[0];
#pragma unroll
    for (int j = 1; j < 9; ++j) mn = fminf(mn, D[j]);
    float xk = -(mn / 12.0f) * 1000.0f;
    float nm = fmaxf(M, xk);
    float sc = expf(M - nm);
    float ek = expf(xk - nm);
    den = den * sc + ek;
    ax = ax * sc + ox * ek;
    ay = ay * sc + oy * ek;
    M = nm;
  }
  float resx = ax / den;
  float resy = ay / den;
  out[p] = fminf(fmaxf(resx + lx, 0.0f), 511.0f) - lx;
  out[B_ * HW_ + p] = fminf(fmaxf(resy + ly, 0.0f), 511.0f) - ly;
}

extern "C" void kernel_launch(void* const* d_in, const int* in_sizes, int n_in,
                              void* d_out, int out_size, void* d_ws, size_t ws_size,
                              hipStream_t stream) {
  const float* features = (const float*)d_in[0];
  const float* offset_x = (const float*)d_in[1];
  const float* offset_y = (const float*)d_in[2];
  float* out = (float*)d_out;

  const int npix = B_ * HW_;  // 524288
  const size_t need = (size_t)npix * C_ * sizeof(float);  // 75.5 MB

  if (ws_size >= need) {
    float* featT = (float*)d_ws;
    transpose_kernel<<<B_ * H_ * (W_ / 64), 256, 0, stream>>>(features, featT);
    eval_kernel_cw<<<npix / 256, 256, 0, stream>>>(featT, offset_x, offset_y, out);
  } else {
    eval_kernel_n<<<npix / 256, 256, 0, stream>>>(features, offset_x, offset_y, out);
  }
}